// Round 1
// baseline (206.699 us; speedup 1.0000x reference)
//
#include <hip/hip_runtime.h>
#include <math.h>

// Problem dims
#define BATCH 64
#define HI 224
#define WI 224
#define CI0 3
// conv1: 7x7, 3->8, out 218x218, pool -> 109x109
#define P1H 109
#define P1W 109
#define C1 8
// conv2: 5x5, 8->10, out 105x105, pool -> 52x52
#define P2H 52
#define P2W 52
#define C2 10
#define FLATD (P2H*P2W*C2)   // 27040

// ---------------------------------------------------------------------------
// Kernel 1: conv1 (7x7x3->8, VALID) + bias + relu + maxpool2, fused.
// One thread per pooled output (b, ph, pw); computes all 8 co.
// relu(max(a)+bias) == max(relu(a+bias)) since bias const per co, relu monotone.
__global__ __launch_bounds__(256) void conv1_pool_kernel(
    const float* __restrict__ x,      // [B,224,224,3]
    const float* __restrict__ w,      // [7,7,3,8] HWIO
    const float* __restrict__ bias,   // [8]
    float* __restrict__ out)          // [B,109,109,8]
{
    __shared__ float wl[7*7*3*8];     // 1176 floats
    __shared__ float bl[8];
    const int tid = threadIdx.x;
    for (int i = tid; i < 7*7*3*8; i += 256) wl[i] = w[i];
    if (tid < 8) bl[tid] = bias[tid];
    __syncthreads();

    const int tx = tid & 15, ty = tid >> 4;
    const int pw = blockIdx.x * 16 + tx;
    const int ph = blockIdx.y * 16 + ty;
    const int b  = blockIdx.z;
    if (ph >= P1H || pw >= P1W) return;

    float acc[2][2][8];
#pragma unroll
    for (int i = 0; i < 2; ++i)
#pragma unroll
        for (int j = 0; j < 2; ++j)
#pragma unroll
            for (int c = 0; c < 8; ++c) acc[i][j][c] = 0.f;

    const int ih0 = 2*ph, iw0 = 2*pw;
    for (int rr = 0; rr < 8; ++rr) {
        const float* xrow = x + ((size_t)(b*HI + (ih0+rr))*WI + iw0)*CI0;
        float row[24];                // 8 cols x 3 ch
#pragma unroll
        for (int j = 0; j < 24; ++j) row[j] = xrow[j];
#pragma unroll
        for (int ph2 = 0; ph2 < 2; ++ph2) {
            const int kh = rr - ph2;
            if (kh < 0 || kh > 6) continue;
#pragma unroll
            for (int kw = 0; kw < 7; ++kw) {
#pragma unroll
                for (int ci = 0; ci < 3; ++ci) {
                    const float* wp = &wl[((kh*7 + kw)*3 + ci)*8];
                    const float v0 = row[(kw+0)*3 + ci];
                    const float v1 = row[(kw+1)*3 + ci];
#pragma unroll
                    for (int co = 0; co < 8; ++co) {
                        const float wv = wp[co];
                        acc[ph2][0][co] = fmaf(v0, wv, acc[ph2][0][co]);
                        acc[ph2][1][co] = fmaf(v1, wv, acc[ph2][1][co]);
                    }
                }
            }
        }
    }

    float* op = out + ((size_t)(b*P1H + ph)*P1W + pw)*C1;
#pragma unroll
    for (int co = 0; co < 8; ++co) {
        float m = fmaxf(fmaxf(acc[0][0][co], acc[0][1][co]),
                        fmaxf(acc[1][0][co], acc[1][1][co]));
        op[co] = fmaxf(m + bl[co], 0.f);
    }
}

// ---------------------------------------------------------------------------
// Kernel 2: conv2 (5x5x8->10, VALID) + bias + relu + maxpool2, fused.
// One thread per pooled output (b, ph, pw); computes all 10 co.
__global__ __launch_bounds__(256) void conv2_pool_kernel(
    const float* __restrict__ p1,     // [B,109,109,8]
    const float* __restrict__ w,      // [5,5,8,10] HWIO
    const float* __restrict__ bias,   // [10]
    float* __restrict__ out)          // [B,52,52,10]
{
    __shared__ float wl[5*5*8*16];    // padded co-stride 16 for aligned b128 reads
    __shared__ float bl[10];
    const int tid = threadIdx.x;
    for (int i = tid; i < 5*5*8*10; i += 256) {
        const int vec = i / 10, co = i % 10;
        wl[vec*16 + co] = w[i];
    }
    if (tid < 10) bl[tid] = bias[tid];
    __syncthreads();

    const int tx = tid & 15, ty = tid >> 4;
    const int pw = blockIdx.x * 16 + tx;
    const int ph = blockIdx.y * 16 + ty;
    const int b  = blockIdx.z;
    if (ph >= P2H || pw >= P2W) return;

    float acc[2][2][10];
#pragma unroll
    for (int i = 0; i < 2; ++i)
#pragma unroll
        for (int j = 0; j < 2; ++j)
#pragma unroll
            for (int c = 0; c < 10; ++c) acc[i][j][c] = 0.f;

    const int ih0 = 2*ph, iw0 = 2*pw;
    for (int rr = 0; rr < 6; ++rr) {
        const float* xrow = p1 + ((size_t)(b*P1H + (ih0+rr))*P1W + iw0)*C1;
        float row[48];                // 6 cols x 8 ch
#pragma unroll
        for (int j = 0; j < 48; ++j) row[j] = xrow[j];
#pragma unroll
        for (int ph2 = 0; ph2 < 2; ++ph2) {
            const int kh = rr - ph2;
            if (kh < 0 || kh > 4) continue;
#pragma unroll
            for (int kw = 0; kw < 5; ++kw) {
#pragma unroll
                for (int ci = 0; ci < 8; ++ci) {
                    const float* wp = &wl[((kh*5 + kw)*8 + ci)*16];
                    const float v0 = row[(kw+0)*8 + ci];
                    const float v1 = row[(kw+1)*8 + ci];
#pragma unroll
                    for (int co = 0; co < 10; ++co) {
                        const float wv = wp[co];
                        acc[ph2][0][co] = fmaf(v0, wv, acc[ph2][0][co]);
                        acc[ph2][1][co] = fmaf(v1, wv, acc[ph2][1][co]);
                    }
                }
            }
        }
    }

    float* op = out + ((size_t)(b*P2H + ph)*P2W + pw)*C2;
#pragma unroll
    for (int co = 0; co < 10; ++co) {
        float m = fmaxf(fmaxf(acc[0][0][co], acc[0][1][co]),
                        fmaxf(acc[1][0][co], acc[1][1][co]));
        op[co] = fmaxf(m + bl[co], 0.f);
    }
}

// ---------------------------------------------------------------------------
// Kernel 3: FC  theta[b,k] = sum_f feat[b,f]*fw[f,k] + fb[k].  One block per b.
__global__ __launch_bounds__(256) void fc_kernel(
    const float* __restrict__ feat,   // [B, 27040] (== p2 flattened row-major)
    const float* __restrict__ fw,     // [27040, 6]
    const float* __restrict__ fb,     // [6]
    float* __restrict__ theta)        // [B, 6]
{
    const int b = blockIdx.x;
    const float* f = feat + (size_t)b * FLATD;
    float acc[6] = {0.f, 0.f, 0.f, 0.f, 0.f, 0.f};
    for (int i = threadIdx.x; i < FLATD; i += 256) {
        const float v = f[i];
        const float* wp = fw + (size_t)i * 6;
#pragma unroll
        for (int k = 0; k < 6; ++k) acc[k] = fmaf(v, wp[k], acc[k]);
    }
    __shared__ float red[4][6];
#pragma unroll
    for (int k = 0; k < 6; ++k) {
        float v = acc[k];
        for (int off = 32; off > 0; off >>= 1) v += __shfl_down(v, off);
        if ((threadIdx.x & 63) == 0) red[threadIdx.x >> 6][k] = v;
    }
    __syncthreads();
    if (threadIdx.x < 6) {
        const int k = threadIdx.x;
        theta[b*6 + k] = red[0][k] + red[1][k] + red[2][k] + red[3][k] + fb[k];
    }
}

// ---------------------------------------------------------------------------
// Kernel 4: affine bilinear resample, ImageProjectiveTransformV3 semantics.
// x_in = a0*x_out + a1*y_out + a2 ; y_in = a3*x_out + a4*y_out + a5
// each of the 4 corner reads is zero-filled if OOB.
__global__ __launch_bounds__(256) void resample_kernel(
    const float* __restrict__ x,      // [B,224,224,3]
    const float* __restrict__ theta,  // [B,6]
    float* __restrict__ out)          // [B,224,224,3]
{
    const int idx = blockIdx.x * 256 + threadIdx.x;   // pixel index
    const int total = BATCH * HI * WI;
    if (idx >= total) return;
    const int b   = idx / (HI*WI);
    const int pix = idx - b * (HI*WI);
    const int yo  = pix / WI;
    const int xo  = pix - yo * WI;

    const float* t = theta + b*6;
    const float a0 = t[0], a1 = t[1], a2 = t[2], a3 = t[3], a4 = t[4], a5 = t[5];

    const float fx = (float)xo, fy = (float)yo;
    const float xq = a0*fx + a1*fy + a2;
    const float yq = a3*fx + a4*fy + a5;
    const float x0f = floorf(xq), y0f = floorf(yq);
    const float dx = xq - x0f, dy = yq - y0f;
    const int x0 = (int)x0f, y0 = (int)y0f;

    const float* img = x + (size_t)b * (HI*WI*CI0);

    // corner validity + clamped base offsets
    const int x1 = x0 + 1, y1 = y0 + 1;
    const bool vx0 = (x0 >= 0) && (x0 <= WI-1);
    const bool vx1 = (x1 >= 0) && (x1 <= WI-1);
    const bool vy0 = (y0 >= 0) && (y0 <= HI-1);
    const bool vy1 = (y1 >= 0) && (y1 <= HI-1);
    const int xc0 = min(max(x0, 0), WI-1);
    const int xc1 = min(max(x1, 0), WI-1);
    const int yc0 = min(max(y0, 0), HI-1);
    const int yc1 = min(max(y1, 0), HI-1);
    const float* p00 = img + (size_t)(yc0*WI + xc0)*CI0;
    const float* p01 = img + (size_t)(yc0*WI + xc1)*CI0;
    const float* p10 = img + (size_t)(yc1*WI + xc0)*CI0;
    const float* p11 = img + (size_t)(yc1*WI + xc1)*CI0;
    const float m00 = (vy0 && vx0) ? 1.f : 0.f;
    const float m01 = (vy0 && vx1) ? 1.f : 0.f;
    const float m10 = (vy1 && vx0) ? 1.f : 0.f;
    const float m11 = (vy1 && vx1) ? 1.f : 0.f;

    float* op = out + (size_t)idx * CI0;
#pragma unroll
    for (int c = 0; c < CI0; ++c) {
        const float v00 = m00 * p00[c];
        const float v01 = m01 * p01[c];
        const float v10 = m10 * p10[c];
        const float v11 = m11 * p11[c];
        const float top = v00 * (1.f - dx) + v01 * dx;
        const float bot = v10 * (1.f - dx) + v11 * dx;
        op[c] = top * (1.f - dy) + bot * dy;
    }
}

// ---------------------------------------------------------------------------
extern "C" void kernel_launch(void* const* d_in, const int* in_sizes, int n_in,
                              void* d_out, int out_size, void* d_ws, size_t ws_size,
                              hipStream_t stream) {
    const float* x   = (const float*)d_in[0];
    const float* w1  = (const float*)d_in[1];
    const float* b1  = (const float*)d_in[2];
    const float* w2  = (const float*)d_in[3];
    const float* b2  = (const float*)d_in[4];
    const float* fw  = (const float*)d_in[5];
    const float* fb  = (const float*)d_in[6];
    float* out = (float*)d_out;

    char* ws = (char*)d_ws;
    const size_t P1_BYTES = (size_t)BATCH * P1H * P1W * C1 * sizeof(float); // 24,326,144
    const size_t P2_BYTES = (size_t)BATCH * P2H * P2W * C2 * sizeof(float); //  6,922,240
    float* p1 = (float*)ws;
    float* p2 = (float*)(ws + P1_BYTES);
    float* th = (float*)(ws + P1_BYTES + P2_BYTES);

    conv1_pool_kernel<<<dim3((P1W+15)/16, (P1H+15)/16, BATCH), 256, 0, stream>>>(x, w1, b1, p1);
    conv2_pool_kernel<<<dim3((P2W+15)/16, (P2H+15)/16, BATCH), 256, 0, stream>>>(p1, w2, b2, p2);
    fc_kernel<<<dim3(BATCH), 256, 0, stream>>>(p2, fw, fb, th);

    const int total_pix = BATCH * HI * WI;
    resample_kernel<<<dim3((total_pix + 255)/256), 256, 0, stream>>>(x, th, out);
}

// Round 2
// 204.102 us; speedup vs baseline: 1.0127x; 1.0127x over previous
//
#include <hip/hip_runtime.h>
#include <math.h>

// Problem dims
#define BATCH 64
#define HI 224
#define WI 224
#define CI0 3
// conv1: 7x7, 3->8, out 218x218, pool -> 109x109
#define P1H 109
#define P1W 109
#define C1 8
// conv2: 5x5, 8->10, out 105x105, pool -> 52x52
#define P2H 52
#define P2W 52
#define C2 10
#define FLATD (P2H*P2W*C2)   // 27040

// ---------------------------------------------------------------------------
// Kernel 1: conv1 (7x7x3->8) + bias + relu + maxpool2, fused.
// One thread per PAIR of pooled outputs in w (4 conv cols) -> each weight
// ds_read feeds 32 FMAs (was 16). relu(max(a)+b) == max(relu(a+b)).
#define C1PAIRS 55                   // ceil(109/2); pair 54 has 1 valid output
#define C1WORK (C1PAIRS * P1H)       // 5995 threads per image
__global__ __launch_bounds__(256) void conv1_pool_kernel(
    const float* __restrict__ x,      // [B,224,224,3]
    const float* __restrict__ w,      // [7,7,3,8] HWIO
    const float* __restrict__ bias,   // [8]
    float* __restrict__ out)          // [B,109,109,8]
{
    __shared__ float wl[7*7*3*8];     // 1176 floats, co contiguous (32B vectors)
    __shared__ float bl[8];
    const int tid = threadIdx.x;
    for (int i = tid; i < 7*7*3*8; i += 256) wl[i] = w[i];
    if (tid < 8) bl[tid] = bias[tid];
    __syncthreads();

    const int id = blockIdx.x * 256 + tid;
    if (id >= C1WORK) return;
    const int b   = blockIdx.y;
    const int ph  = id / C1PAIRS;
    const int pwp = id - ph * C1PAIRS;
    const int iw0 = 4 * pwp;          // input col base (multiple of 4 -> 16B aligned)
    const int ih0 = 2 * ph;
    const bool edge = (pwp == C1PAIRS - 1);  // needs cols 216..225; 224,225 OOB

    float acc[2][4][8];
#pragma unroll
    for (int i = 0; i < 2; ++i)
#pragma unroll
        for (int j = 0; j < 4; ++j)
#pragma unroll
            for (int c = 0; c < 8; ++c) acc[i][j][c] = 0.f;

    for (int rr = 0; rr < 8; ++rr) {
        const float* xrow = x + ((size_t)(b*HI + (ih0+rr))*WI + iw0)*CI0;
        float row[30];                // 10 cols x 3 ch
        if (!edge) {
#pragma unroll
            for (int j = 0; j < 7; ++j) {
                const float4 v = *(const float4*)(xrow + 4*j);
                row[4*j+0] = v.x; row[4*j+1] = v.y; row[4*j+2] = v.z; row[4*j+3] = v.w;
            }
            const float2 v = *(const float2*)(xrow + 28);
            row[28] = v.x; row[29] = v.y;
        } else {
#pragma unroll
            for (int j = 0; j < 30; ++j) {
                const int col = iw0 + j/3;
                row[j] = (col < WI) ? xrow[j] : 0.f;
            }
        }
#pragma unroll
        for (int ph2 = 0; ph2 < 2; ++ph2) {
            const int kh = rr - ph2;
            if (kh < 0 || kh > 6) continue;
#pragma unroll
            for (int kw = 0; kw < 7; ++kw) {
#pragma unroll
                for (int ci = 0; ci < 3; ++ci) {
                    const float* wp = &wl[((kh*7 + kw)*3 + ci)*8];
                    const float v0 = row[(kw+0)*3 + ci];
                    const float v1 = row[(kw+1)*3 + ci];
                    const float v2 = row[(kw+2)*3 + ci];
                    const float v3 = row[(kw+3)*3 + ci];
#pragma unroll
                    for (int co = 0; co < 8; ++co) {
                        const float wv = wp[co];
                        acc[ph2][0][co] = fmaf(v0, wv, acc[ph2][0][co]);
                        acc[ph2][1][co] = fmaf(v1, wv, acc[ph2][1][co]);
                        acc[ph2][2][co] = fmaf(v2, wv, acc[ph2][2][co]);
                        acc[ph2][3][co] = fmaf(v3, wv, acc[ph2][3][co]);
                    }
                }
            }
        }
    }

#pragma unroll
    for (int p = 0; p < 2; ++p) {
        const int pw = 2*pwp + p;
        if (pw >= P1W) break;         // pwp==54, p==1
        float* op = out + ((size_t)(b*P1H + ph)*P1W + pw)*C1;
        float4 o0, o1;
        float tmp[8];
#pragma unroll
        for (int co = 0; co < 8; ++co) {
            const float m = fmaxf(fmaxf(acc[0][2*p][co], acc[0][2*p+1][co]),
                                  fmaxf(acc[1][2*p][co], acc[1][2*p+1][co]));
            tmp[co] = fmaxf(m + bl[co], 0.f);
        }
        o0.x = tmp[0]; o0.y = tmp[1]; o0.z = tmp[2]; o0.w = tmp[3];
        o1.x = tmp[4]; o1.y = tmp[5]; o1.z = tmp[6]; o1.w = tmp[7];
        *(float4*)(op)     = o0;
        *(float4*)(op + 4) = o1;
    }
}

// ---------------------------------------------------------------------------
// Kernel 2: conv2 (5x5x8->10) + bias + relu + maxpool2, fused.
// One thread per PAIR of pooled outputs in w (4 conv cols).
#define C2PAIRS 26                   // 52/2, exact
#define C2WORK (C2PAIRS * P2H)       // 1352 per image
__global__ __launch_bounds__(256) void conv2_pool_kernel(
    const float* __restrict__ p1,     // [B,109,109,8]
    const float* __restrict__ w,      // [5,5,8,10] HWIO
    const float* __restrict__ bias,   // [10]
    float* __restrict__ out)          // [B,52,52,10]
{
    __shared__ float wl[5*5*8*16];    // co-stride padded to 16
    __shared__ float bl[10];
    const int tid = threadIdx.x;
    for (int i = tid; i < 5*5*8*10; i += 256) {
        const int vec = i / 10, co = i % 10;
        wl[vec*16 + co] = w[i];
    }
    if (tid < 10) bl[tid] = bias[tid];
    __syncthreads();

    const int id = blockIdx.x * 256 + tid;
    if (id >= C2WORK) return;
    const int b   = blockIdx.y;
    const int ph  = id / C2PAIRS;
    const int pwp = id - ph * C2PAIRS;
    const int iw0 = 4 * pwp;          // <=100; cols iw0..iw0+7 <= 107 < 109, no OOB
    const int ih0 = 2 * ph;           // rows ih0..ih0+5 <= 107 < 109

    float acc[2][4][10];
#pragma unroll
    for (int i = 0; i < 2; ++i)
#pragma unroll
        for (int j = 0; j < 4; ++j)
#pragma unroll
            for (int c = 0; c < 10; ++c) acc[i][j][c] = 0.f;

    for (int rr = 0; rr < 6; ++rr) {
        const float* xrow = p1 + ((size_t)(b*P1H + (ih0+rr))*P1W + iw0)*C1;
        float row[64];                // 8 cols x 8 ch; base 32B-aligned
#pragma unroll
        for (int j = 0; j < 16; ++j) {
            const float4 v = *(const float4*)(xrow + 4*j);
            row[4*j+0] = v.x; row[4*j+1] = v.y; row[4*j+2] = v.z; row[4*j+3] = v.w;
        }
#pragma unroll
        for (int ph2 = 0; ph2 < 2; ++ph2) {
            const int kh = rr - ph2;
            if (kh < 0 || kh > 4) continue;
#pragma unroll
            for (int kw = 0; kw < 5; ++kw) {
#pragma unroll
                for (int ci = 0; ci < 8; ++ci) {
                    const float* wp = &wl[((kh*5 + kw)*8 + ci)*16];
                    const float v0 = row[(kw+0)*8 + ci];
                    const float v1 = row[(kw+1)*8 + ci];
                    const float v2 = row[(kw+2)*8 + ci];
                    const float v3 = row[(kw+3)*8 + ci];
#pragma unroll
                    for (int co = 0; co < 10; ++co) {
                        const float wv = wp[co];
                        acc[ph2][0][co] = fmaf(v0, wv, acc[ph2][0][co]);
                        acc[ph2][1][co] = fmaf(v1, wv, acc[ph2][1][co]);
                        acc[ph2][2][co] = fmaf(v2, wv, acc[ph2][2][co]);
                        acc[ph2][3][co] = fmaf(v3, wv, acc[ph2][3][co]);
                    }
                }
            }
        }
    }

#pragma unroll
    for (int p = 0; p < 2; ++p) {
        const int pw = 2*pwp + p;
        float* op = out + ((size_t)(b*P2H + ph)*P2W + pw)*C2;
#pragma unroll
        for (int co = 0; co < 10; ++co) {
            const float m = fmaxf(fmaxf(acc[0][2*p][co], acc[0][2*p+1][co]),
                                  fmaxf(acc[1][2*p][co], acc[1][2*p+1][co]));
            op[co] = fmaxf(m + bl[co], 0.f);
        }
    }
}

// ---------------------------------------------------------------------------
// Kernel 3: FC  theta[b,k] = sum_f feat[b,f]*fw[f,k] + fb[k].  One block per b.
__global__ __launch_bounds__(256) void fc_kernel(
    const float* __restrict__ feat,   // [B, 27040]
    const float* __restrict__ fw,     // [27040, 6]
    const float* __restrict__ fb,     // [6]
    float* __restrict__ theta)        // [B, 6]
{
    const int b = blockIdx.x;
    const float* f = feat + (size_t)b * FLATD;
    float acc[6] = {0.f, 0.f, 0.f, 0.f, 0.f, 0.f};
    for (int i = threadIdx.x; i < FLATD; i += 256) {
        const float v = f[i];
        const float* wp = fw + (size_t)i * 6;
#pragma unroll
        for (int k = 0; k < 6; ++k) acc[k] = fmaf(v, wp[k], acc[k]);
    }
    __shared__ float red[4][6];
#pragma unroll
    for (int k = 0; k < 6; ++k) {
        float v = acc[k];
        for (int off = 32; off > 0; off >>= 1) v += __shfl_down(v, off);
        if ((threadIdx.x & 63) == 0) red[threadIdx.x >> 6][k] = v;
    }
    __syncthreads();
    if (threadIdx.x < 6) {
        const int k = threadIdx.x;
        theta[b*6 + k] = red[0][k] + red[1][k] + red[2][k] + red[3][k] + fb[k];
    }
}

// ---------------------------------------------------------------------------
// Kernel 4: affine bilinear resample, ImageProjectiveTransformV3 semantics.
__global__ __launch_bounds__(256) void resample_kernel(
    const float* __restrict__ x,      // [B,224,224,3]
    const float* __restrict__ theta,  // [B,6]
    float* __restrict__ out)          // [B,224,224,3]
{
    const int idx = blockIdx.x * 256 + threadIdx.x;   // pixel index
    const int total = BATCH * HI * WI;
    if (idx >= total) return;
    const int b   = idx / (HI*WI);
    const int pix = idx - b * (HI*WI);
    const int yo  = pix / WI;
    const int xo  = pix - yo * WI;

    const float* t = theta + b*6;
    const float a0 = t[0], a1 = t[1], a2 = t[2], a3 = t[3], a4 = t[4], a5 = t[5];

    const float fx = (float)xo, fy = (float)yo;
    const float xq = a0*fx + a1*fy + a2;
    const float yq = a3*fx + a4*fy + a5;
    const float x0f = floorf(xq), y0f = floorf(yq);
    const float dx = xq - x0f, dy = yq - y0f;
    const int x0 = (int)x0f, y0 = (int)y0f;

    const float* img = x + (size_t)b * (HI*WI*CI0);

    const int x1 = x0 + 1, y1 = y0 + 1;
    const bool vx0 = (x0 >= 0) && (x0 <= WI-1);
    const bool vx1 = (x1 >= 0) && (x1 <= WI-1);
    const bool vy0 = (y0 >= 0) && (y0 <= HI-1);
    const bool vy1 = (y1 >= 0) && (y1 <= HI-1);
    const int xc0 = min(max(x0, 0), WI-1);
    const int xc1 = min(max(x1, 0), WI-1);
    const int yc0 = min(max(y0, 0), HI-1);
    const int yc1 = min(max(y1, 0), HI-1);
    const float* p00 = img + (size_t)(yc0*WI + xc0)*CI0;
    const float* p01 = img + (size_t)(yc0*WI + xc1)*CI0;
    const float* p10 = img + (size_t)(yc1*WI + xc0)*CI0;
    const float* p11 = img + (size_t)(yc1*WI + xc1)*CI0;
    const float m00 = (vy0 && vx0) ? 1.f : 0.f;
    const float m01 = (vy0 && vx1) ? 1.f : 0.f;
    const float m10 = (vy1 && vx0) ? 1.f : 0.f;
    const float m11 = (vy1 && vx1) ? 1.f : 0.f;

    float* op = out + (size_t)idx * CI0;
#pragma unroll
    for (int c = 0; c < CI0; ++c) {
        const float v00 = m00 * p00[c];
        const float v01 = m01 * p01[c];
        const float v10 = m10 * p10[c];
        const float v11 = m11 * p11[c];
        const float top = v00 * (1.f - dx) + v01 * dx;
        const float bot = v10 * (1.f - dx) + v11 * dx;
        op[c] = top * (1.f - dy) + bot * dy;
    }
}

// ---------------------------------------------------------------------------
extern "C" void kernel_launch(void* const* d_in, const int* in_sizes, int n_in,
                              void* d_out, int out_size, void* d_ws, size_t ws_size,
                              hipStream_t stream) {
    const float* x   = (const float*)d_in[0];
    const float* w1  = (const float*)d_in[1];
    const float* b1  = (const float*)d_in[2];
    const float* w2  = (const float*)d_in[3];
    const float* b2  = (const float*)d_in[4];
    const float* fw  = (const float*)d_in[5];
    const float* fb  = (const float*)d_in[6];
    float* out = (float*)d_out;

    char* ws = (char*)d_ws;
    const size_t P1_BYTES = (size_t)BATCH * P1H * P1W * C1 * sizeof(float);
    const size_t P2_BYTES = (size_t)BATCH * P2H * P2W * C2 * sizeof(float);
    float* p1 = (float*)ws;
    float* p2 = (float*)(ws + P1_BYTES);
    float* th = (float*)(ws + P1_BYTES + P2_BYTES);

    conv1_pool_kernel<<<dim3((C1WORK + 255)/256, BATCH), 256, 0, stream>>>(x, w1, b1, p1);
    conv2_pool_kernel<<<dim3((C2WORK + 255)/256, BATCH), 256, 0, stream>>>(p1, w2, b2, p2);
    fc_kernel<<<dim3(BATCH), 256, 0, stream>>>(p2, fw, fb, th);

    const int total_pix = BATCH * HI * WI;
    resample_kernel<<<dim3((total_pix + 255)/256), 256, 0, stream>>>(x, th, out);
}

// Round 3
// 150.856 us; speedup vs baseline: 1.3702x; 1.3530x over previous
//
#include <hip/hip_runtime.h>
#include <math.h>

#define BATCH 64
#define HI 224
#define WI 224
#define P1H 109
#define P1W 109
#define P2H 52
#define P2W 52

typedef short bf16x4 __attribute__((ext_vector_type(4)));
typedef short bf16x8 __attribute__((ext_vector_type(8)));
typedef float f32x4  __attribute__((ext_vector_type(4)));

#define MFMA16(a,b,c) __builtin_amdgcn_mfma_f32_16x16x32_bf16((a),(b),(c),0,0,0)

static __device__ __forceinline__ unsigned short f2bf(float f){
    unsigned u = __float_as_uint(f);
    u += 0x7FFFu + ((u >> 16) & 1u);           // RNE
    return (unsigned short)(u >> 16);
}
static __device__ __forceinline__ float bf2f(unsigned short s){
    return __uint_as_float(((unsigned)s) << 16);
}

// ---------------------------------------------------------------------------
// conv1 7x7x3->8 + bias + relu + maxpool2, MFMA 16x16x32 bf16, split-precision.
// Block = one pooled row (conv rows 2ph,2ph+1) x one image. 4 waves, 14 M-tiles.
// Input staged in LDS as bf16 hi/lo, channel-padded to 4 (K per kh-row = 32).
// B packed [w_hi (n=0..7) | w_lo (n=8..15)]; 2 MFMA passes per K-chunk give
// x_hi*w_hi + x_lo*w_hi (cols 0-7) and x_hi*w_lo + x_lo*w_lo (cols 8-15);
// total = acc[co] + acc[co+8] == (x_hi+x_lo)*(w_hi+w_lo).
__global__ __launch_bounds__(256) void conv1_kernel(
    const float* __restrict__ x, const float* __restrict__ w1,
    const float* __restrict__ b1,
    unsigned short* __restrict__ p1h, unsigned short* __restrict__ p1l)
{
    __shared__ char smem[14336 + 14336 + 7168 + 128];
    short* sh_hi = (short*)smem;                 // [8 rows][224 cols][4 ch] bf16
    short* sh_lo = (short*)(smem + 14336);
    short* sh_b  = (short*)(smem + 28672);       // [16 n][224 k] bf16

    const int tid = threadIdx.x;
    const int ph  = blockIdx.x;                  // 0..108
    const int b   = blockIdx.y;

    for (int i = tid; i < 3584; i += 256) sh_b[i] = 0;
    __syncthreads();

    // fill B: w1 HWIO (7,7,3,8); k = kh*32 + kw*4 + ci
    for (int i = tid; i < 1176; i += 256) {
        const float v = w1[i];
        const int kh = i / 168;
        int rem = i - kh*168;
        const int kw = rem / 24;
        rem -= kw*24;
        const int ci = rem / 8;
        const int co = rem - ci*8;
        const int k  = kh*32 + kw*4 + ci;
        const unsigned short h = f2bf(v);
        sh_b[co*224 + k]     = (short)h;
        sh_b[(co+8)*224 + k] = (short)f2bf(v - bf2f(h));
    }

    // stage x rows 2ph..2ph+7 (contiguous 5376 floats), cvt to hi/lo bf16, ch4-pad
    const float* xb = x + ((size_t)b*HI + 2*ph) * (WI*3);
    for (int e = tid; e < 5376; e += 256) {
        const float v = xb[e];
        const int row = e / 672;
        const int rem = e - row*672;
        const int col = rem / 3;
        const int ci  = rem - col*3;
        const int si  = row*896 + col*4 + ci;
        const unsigned short h = f2bf(v);
        sh_hi[si] = (short)h;
        sh_lo[si] = (short)f2bf(v - bf2f(h));
    }
    for (int i = tid; i < 1792; i += 256) {      // ci==3 pad slots -> 0 (avoid NaN*0)
        sh_hi[i*4+3] = 0;
        sh_lo[i*4+3] = 0;
    }
    __syncthreads();

    const int lane = tid & 63;
    const int wave = tid >> 6;
    const int n16  = lane & 15;                  // N (co / co+8)
    const int g    = lane >> 4;                  // k-block group

    bf16x8 bw[7];
#pragma unroll
    for (int j = 0; j < 7; ++j)
        bw[j] = *(const bf16x8*)(sh_b + n16*224 + j*32 + g*8);
    const float bias = (n16 < 8) ? b1[n16] : 0.f;

    for (int t = wave; t < 14; t += 4) {
        const int c0 = t*16;
        const int p4 = (c0 + n16)*4 + g*8;       // short index base within a row
        float res[2][4];
#pragma unroll
        for (int ro = 0; ro < 2; ++ro) {         // conv rows 2ph+ro
            f32x4 accA = {0.f,0.f,0.f,0.f};
            f32x4 accB = {0.f,0.f,0.f,0.f};
#pragma unroll
            for (int j = 0; j < 7; ++j) {        // kh = j, K-chunk of 32
                const int si = (ro + j)*896 + p4;
                bf16x4 h0 = *(const bf16x4*)(sh_hi + si);
                bf16x4 h1 = *(const bf16x4*)(sh_hi + si + 4);
                bf16x4 l0 = *(const bf16x4*)(sh_lo + si);
                bf16x4 l1 = *(const bf16x4*)(sh_lo + si + 4);
                const bf16x8 ah = __builtin_shufflevector(h0, h1, 0,1,2,3,4,5,6,7);
                const bf16x8 al = __builtin_shufflevector(l0, l1, 0,1,2,3,4,5,6,7);
                if (j & 1) {
                    accB = MFMA16(ah, bw[j], accB);
                    accB = MFMA16(al, bw[j], accB);
                } else {
                    accA = MFMA16(ah, bw[j], accA);
                    accA = MFMA16(al, bw[j], accA);
                }
            }
#pragma unroll
            for (int r = 0; r < 4; ++r) {
                const float s = accA[r] + accB[r];
                res[ro][r] = s + __shfl_xor(s, 8);   // add partner column co+8
            }
        }
        if (n16 < 8) {
#pragma unroll
            for (int q = 0; q < 2; ++q) {
                const int pc = (c0 >> 1) + 2*g + q;  // pooled col
                if (pc < P1W) {
                    float m = fmaxf(fmaxf(res[0][2*q], res[0][2*q+1]),
                                    fmaxf(res[1][2*q], res[1][2*q+1]));
                    m = fmaxf(m + bias, 0.f);
                    const size_t oi = ((size_t)((b*P1H + ph)*P1W) + pc)*8 + n16;
                    const unsigned short hh = f2bf(m);
                    p1h[oi] = hh;
                    p1l[oi] = f2bf(m - bf2f(hh));
                }
            }
        }
    }
}

// ---------------------------------------------------------------------------
// conv2 5x5x8->10 + bias + relu + maxpool2, MFMA, 3-pass split.
// K = kh*40 + kw*8 + ci (=200, pad to 224); 8-chunks are 16B-aligned in p1 rows.
__global__ __launch_bounds__(256) void conv2_kernel(
    const unsigned short* __restrict__ p1h, const unsigned short* __restrict__ p1l,
    const float* __restrict__ w2, const float* __restrict__ b2,
    float* __restrict__ p2)
{
    __shared__ char smem[10752 + 10752 + 7168 + 7168 + 128];
    short* sh_hi = (short*)smem;                 // 6 p1 rows (872 shorts each) + tail
    short* sh_lo = (short*)(smem + 10752);
    short* sh_bh = (short*)(smem + 21504);       // [16 n][224 k]
    short* sh_bl = (short*)(smem + 28672);

    const int tid = threadIdx.x;
    const int ph  = blockIdx.x;                  // 0..51
    const int b   = blockIdx.y;

    for (int i = tid; i < 7168; i += 256) ((short*)(smem + 21504))[i] = 0;
    __syncthreads();

    for (int i = tid; i < 2000; i += 256) {      // w2 HWIO (5,5,8,10)
        const float v = w2[i];
        const int kh = i / 400;
        int rem = i - kh*400;
        const int kw = rem / 80;
        rem -= kw*80;
        const int ci = rem / 10;
        const int co = rem - ci*10;
        const int k  = kh*40 + kw*8 + ci;
        const unsigned short h = f2bf(v);
        sh_bh[co*224 + k] = (short)h;
        sh_bl[co*224 + k] = (short)f2bf(v - bf2f(h));
    }

    // stage p1 rows 2ph..2ph+5 (contiguous, 10464B each array)
    const size_t gbase = ((size_t)b*P1H + 2*ph) * (P1W*8);
    const ulong2* gh = (const ulong2*)(p1h + gbase);
    const ulong2* gl = (const ulong2*)(p1l + gbase);
    ulong2* dh = (ulong2*)sh_hi;
    ulong2* dl = (ulong2*)sh_lo;
    for (int c = tid; c < 654; c += 256) {
        dh[c] = gh[c];
        dl[c] = gl[c];
    }
    for (int i = tid; i < 144; i += 256) {       // unwritten LDS tails -> 0
        sh_hi[5232 + i] = 0;
        sh_lo[5232 + i] = 0;
    }
    __syncthreads();

    const int lane = tid & 63;
    const int wave = tid >> 6;
    const int n16  = lane & 15;
    const int g    = lane >> 4;

    bf16x8 bh[7], bl[7];
#pragma unroll
    for (int j = 0; j < 7; ++j) {
        bh[j] = *(const bf16x8*)(sh_bh + n16*224 + j*32 + g*8);
        bl[j] = *(const bf16x8*)(sh_bl + n16*224 + j*32 + g*8);
    }
    const float bias = (n16 < 10) ? b2[n16] : 0.f;

    int koff[7];
#pragma unroll
    for (int j = 0; j < 7; ++j) {                // chunk = 4j+g -> (kh,kw)
        const int chunk = 4*j + g;
        const int kh = chunk / 5;
        const int kw = chunk - kh*5;
        koff[j] = kh*872 + kw*8;                 // short offset
    }

    for (int t = wave; t < 7; t += 4) {
        const int c0 = t*16;
        const int pbase = (c0 + n16)*8;
        float res[2][4];
#pragma unroll
        for (int ro = 0; ro < 2; ++ro) {
            f32x4 accA = {0.f,0.f,0.f,0.f};
            f32x4 accB = {0.f,0.f,0.f,0.f};
            const int rb = ro*872 + pbase;
#pragma unroll
            for (int j = 0; j < 7; ++j) {
                const int si = rb + koff[j];
                const bf16x8 ah = *(const bf16x8*)(sh_hi + si);
                const bf16x8 al = *(const bf16x8*)(sh_lo + si);
                if (j & 1) {
                    accB = MFMA16(ah, bh[j], accB);
                    accB = MFMA16(al, bh[j], accB);
                    accB = MFMA16(ah, bl[j], accB);
                } else {
                    accA = MFMA16(ah, bh[j], accA);
                    accA = MFMA16(al, bh[j], accA);
                    accA = MFMA16(ah, bl[j], accA);
                }
            }
#pragma unroll
            for (int r = 0; r < 4; ++r) res[ro][r] = accA[r] + accB[r];
        }
        if (n16 < 10) {
#pragma unroll
            for (int q = 0; q < 2; ++q) {
                const int pc = (c0 >> 1) + 2*g + q;
                if (pc < P2W) {
                    float m = fmaxf(fmaxf(res[0][2*q], res[0][2*q+1]),
                                    fmaxf(res[1][2*q], res[1][2*q+1]));
                    p2[((size_t)((b*P2H + ph)*P2W) + pc)*10 + n16] = fmaxf(m + bias, 0.f);
                }
            }
        }
    }
}

// ---------------------------------------------------------------------------
// FC stage A: partial[b][s][6] over K-slices of 3380. Deterministic (no atomics).
__global__ __launch_bounds__(256) void fcA_kernel(
    const float* __restrict__ p2, const float* __restrict__ fw,
    float* __restrict__ partial)
{
    const int s = blockIdx.x;                    // 0..7
    const int b = blockIdx.y;
    const int base = s * 3380;
    const float* f = p2 + (size_t)b*27040;
    float acc[6] = {0.f,0.f,0.f,0.f,0.f,0.f};
    for (int i = threadIdx.x; i < 3380; i += 256) {
        const float v = f[base + i];
        const float* wp = fw + (size_t)(base + i)*6;
#pragma unroll
        for (int k = 0; k < 6; ++k) acc[k] = fmaf(v, wp[k], acc[k]);
    }
    __shared__ float red[4][6];
#pragma unroll
    for (int k = 0; k < 6; ++k) {
        float v = acc[k];
        for (int off = 32; off > 0; off >>= 1) v += __shfl_down(v, off);
        if ((threadIdx.x & 63) == 0) red[threadIdx.x >> 6][k] = v;
    }
    __syncthreads();
    if (threadIdx.x < 6) {
        const int k = threadIdx.x;
        partial[(b*8 + s)*6 + k] = red[0][k] + red[1][k] + red[2][k] + red[3][k];
    }
}

__global__ __launch_bounds__(384) void fcB_kernel(
    const float* __restrict__ partial, const float* __restrict__ fb,
    float* __restrict__ theta)
{
    const int t = threadIdx.x;                   // 0..383
    const int b = t / 6, k = t - b*6;
    float s = fb[k];
#pragma unroll
    for (int j = 0; j < 8; ++j) s += partial[(b*8 + j)*6 + k];
    theta[b*6 + k] = s;
}

// ---------------------------------------------------------------------------
// affine bilinear resample, ImageProjectiveTransformV3 semantics (unchanged).
__global__ __launch_bounds__(256) void resample_kernel(
    const float* __restrict__ x, const float* __restrict__ theta,
    float* __restrict__ out)
{
    const int idx = blockIdx.x * 256 + threadIdx.x;
    const int total = BATCH * HI * WI;
    if (idx >= total) return;
    const int b   = idx / (HI*WI);
    const int pix = idx - b * (HI*WI);
    const int yo  = pix / WI;
    const int xo  = pix - yo * WI;

    const float* t = theta + b*6;
    const float a0 = t[0], a1 = t[1], a2 = t[2], a3 = t[3], a4 = t[4], a5 = t[5];

    const float fx = (float)xo, fy = (float)yo;
    const float xq = a0*fx + a1*fy + a2;
    const float yq = a3*fx + a4*fy + a5;
    const float x0f = floorf(xq), y0f = floorf(yq);
    const float dx = xq - x0f, dy = yq - y0f;
    const int x0 = (int)x0f, y0 = (int)y0f;

    const float* img = x + (size_t)b * (HI*WI*3);

    const int x1 = x0 + 1, y1 = y0 + 1;
    const bool vx0 = (x0 >= 0) && (x0 <= WI-1);
    const bool vx1 = (x1 >= 0) && (x1 <= WI-1);
    const bool vy0 = (y0 >= 0) && (y0 <= HI-1);
    const bool vy1 = (y1 >= 0) && (y1 <= HI-1);
    const int xc0 = min(max(x0, 0), WI-1);
    const int xc1 = min(max(x1, 0), WI-1);
    const int yc0 = min(max(y0, 0), HI-1);
    const int yc1 = min(max(y1, 0), HI-1);
    const float* p00 = img + (size_t)(yc0*WI + xc0)*3;
    const float* p01 = img + (size_t)(yc0*WI + xc1)*3;
    const float* p10 = img + (size_t)(yc1*WI + xc0)*3;
    const float* p11 = img + (size_t)(yc1*WI + xc1)*3;
    const float m00 = (vy0 && vx0) ? 1.f : 0.f;
    const float m01 = (vy0 && vx1) ? 1.f : 0.f;
    const float m10 = (vy1 && vx0) ? 1.f : 0.f;
    const float m11 = (vy1 && vx1) ? 1.f : 0.f;

    float* op = out + (size_t)idx * 3;
#pragma unroll
    for (int c = 0; c < 3; ++c) {
        const float v00 = m00 * p00[c];
        const float v01 = m01 * p01[c];
        const float v10 = m10 * p10[c];
        const float v11 = m11 * p11[c];
        const float top = v00 * (1.f - dx) + v01 * dx;
        const float bot = v10 * (1.f - dx) + v11 * dx;
        op[c] = top * (1.f - dy) + bot * dy;
    }
}

// ---------------------------------------------------------------------------
extern "C" void kernel_launch(void* const* d_in, const int* in_sizes, int n_in,
                              void* d_out, int out_size, void* d_ws, size_t ws_size,
                              hipStream_t stream) {
    const float* x   = (const float*)d_in[0];
    const float* w1  = (const float*)d_in[1];
    const float* b1  = (const float*)d_in[2];
    const float* w2  = (const float*)d_in[3];
    const float* b2  = (const float*)d_in[4];
    const float* fw  = (const float*)d_in[5];
    const float* fb  = (const float*)d_in[6];
    float* out = (float*)d_out;

    char* ws = (char*)d_ws;
    unsigned short* p1h = (unsigned short*)ws;                 // 12,166,144 B
    unsigned short* p1l = (unsigned short*)(ws + 12166144);    // 12,166,144 B
    float* p2      = (float*)(ws + 24332288);                  //  6,922,240 B
    float* partial = (float*)(ws + 31254528);                  //     12,288 B
    float* th      = (float*)(ws + 31266816);                  //      1,536 B

    conv1_kernel<<<dim3(P1H, BATCH), 256, 0, stream>>>(x, w1, b1, p1h, p1l);
    conv2_kernel<<<dim3(P2H, BATCH), 256, 0, stream>>>(p1h, p1l, w2, b2, p2);
    fcA_kernel<<<dim3(8, BATCH), 256, 0, stream>>>(p2, fw, partial);
    fcB_kernel<<<dim3(1), 384, 0, stream>>>(partial, fb, th);

    const int total_pix = BATCH * HI * WI;
    resample_kernel<<<dim3((total_pix + 255)/256), 256, 0, stream>>>(x, th, out);
}

// Round 4
// 112.841 us; speedup vs baseline: 1.8318x; 1.3369x over previous
//
#include <hip/hip_runtime.h>
#include <math.h>

#define BATCH 64
#define HI 224
#define WI 224
#define P1H 109
#define P1W 109
#define P2H 52
#define P2W 52

typedef short bf16x4 __attribute__((ext_vector_type(4)));
typedef short bf16x8 __attribute__((ext_vector_type(8)));
typedef float f32x4  __attribute__((ext_vector_type(4)));

#define MFMA16(a,b,c) __builtin_amdgcn_mfma_f32_16x16x32_bf16((a),(b),(c),0,0,0)

static __device__ __forceinline__ unsigned short f2bf(float f){
    unsigned u = __float_as_uint(f);
    u += 0x7FFFu + ((u >> 16) & 1u);           // RNE
    return (unsigned short)(u >> 16);
}
static __device__ __forceinline__ float bf2f(unsigned short s){
    return __uint_as_float(((unsigned)s) << 16);
}

// ---------------------------------------------------------------------------
// conv1 7x7x3->8 + bias + relu + maxpool2.  MFMA 16x16x32 bf16, split hi/lo.
// Block = 4 pooled rows (8 conv rows, 14 input rows) x one image; 4 waves.
// Key idea: hold acc for all 8 conv rows; each input-row A-fragment feeds up
// to 7 MFMAs (one per kh) -> 7x fewer LDS reads per MFMA.
// K per input row = kw*4+ci (32 exactly; kw=7 and ci=3 slots have zero weight).
// B packed [w_hi | w_lo]; two passes (A=x_hi, A=x_lo); total via shfl_xor(8).
#define PROWS 4
#define NROWG 28                      // ceil(109/4)
#define SROWS 14                      // input rows per block
#define ROWSH 896                     // shorts per staged row (224 cols * 4)
#define STOT  (SROWS*ROWSH)           // 12544
#define SPAD  12576                   // +32 zero shorts for tile-13 overrun
__global__ __launch_bounds__(256) void conv1_kernel(
    const float* __restrict__ x, const float* __restrict__ w1,
    const float* __restrict__ b1,
    unsigned short* __restrict__ p1h, unsigned short* __restrict__ p1l)
{
    __shared__ short smem[SPAD*2 + 7*16*32];
    short* sh_hi = smem;
    short* sh_lo = smem + SPAD;
    short* sh_b  = smem + 2*SPAD;      // [7 kh][16 n][32 k]

    const int tid  = threadIdx.x;
    const int lane = tid & 63;
    const int wave = tid >> 6;
    const int bph  = blockIdx.x;       // 0..27
    const int b    = blockIdx.y;
    const int ph0  = PROWS*bph;
    const int ir0  = 2*ph0;            // first input row

    for (int i = tid; i < 7*16*32; i += 256) sh_b[i] = 0;
    __syncthreads();

    // weights: w1 HWIO (7,7,3,8) -> sh_b[(kh*16+n)*32 + kw*4 + ci]
    for (int i = tid; i < 1176; i += 256) {
        const float v = w1[i];
        const int co = i & 7;
        const int t3 = i >> 3;         // (kh*7+kw)*3+ci
        const int ci = t3 % 3;
        const int kk = t3 / 3;
        const int kh = kk / 7;
        const int kw = kk - kh*7;
        const unsigned short h = f2bf(v);
        sh_b[(kh*16 + co)*32 + kw*4 + ci]     = (short)h;
        sh_b[(kh*16 + co+8)*32 + kw*4 + ci]   = (short)f2bf(v - bf2f(h));
    }

    // staging: lane handles 8 consecutive dest shorts (=2 cols * 4 slots)
    // dest is LINEAR: q = row*896 + col*4 + ci; 16B vector stores, contiguous.
    for (int u = wave; u < 25; u += 4) {
        const int q = u*512 + lane*8;
        if (q >= SPAD) continue;
        const int row  = q / ROWSH;
        const int rem  = q - row*ROWSH;
        const int col0 = rem >> 2;     // even
        const int ira  = ir0 + row;
        float f0=0.f,f1=0.f,f2=0.f,f3=0.f,f4=0.f,f5=0.f;
        if (q < STOT && ira < HI) {
            const float* src = x + ((size_t)(b*HI + ira)*WI + col0)*3;
            const float2 a = *(const float2*)(src);
            const float2 c = *(const float2*)(src+2);
            const float2 e = *(const float2*)(src+4);
            f0=a.x; f1=a.y; f2=c.x; f3=c.y; f4=e.x; f5=e.y;
        }
        const unsigned short h0=f2bf(f0), h1=f2bf(f1), h2=f2bf(f2);
        const unsigned short h3=f2bf(f3), h4=f2bf(f4), h5=f2bf(f5);
        bf16x8 hv, lv;
        hv[0]=(short)h0; hv[1]=(short)h1; hv[2]=(short)h2; hv[3]=0;
        hv[4]=(short)h3; hv[5]=(short)h4; hv[6]=(short)h5; hv[7]=0;
        lv[0]=(short)f2bf(f0-bf2f(h0)); lv[1]=(short)f2bf(f1-bf2f(h1));
        lv[2]=(short)f2bf(f2-bf2f(h2)); lv[3]=0;
        lv[4]=(short)f2bf(f3-bf2f(h3)); lv[5]=(short)f2bf(f4-bf2f(h4));
        lv[6]=(short)f2bf(f5-bf2f(h5)); lv[7]=0;
        *(bf16x8*)(sh_hi + q) = hv;
        *(bf16x8*)(sh_lo + q) = lv;
    }
    __syncthreads();

    const int n16 = lane & 15;
    const int g   = lane >> 4;

    bf16x8 bw[7];
#pragma unroll
    for (int kh = 0; kh < 7; ++kh)
        bw[kh] = *(const bf16x8*)(sh_b + (kh*16 + n16)*32 + g*8);
    const float bias = b1[n16 & 7];

    for (int t = wave; t < 14; t += 4) {
        const int abase = (t*16 + n16)*4 + g*8;
        f32x4 acc[8];
#pragma unroll
        for (int cr = 0; cr < 8; ++cr) acc[cr] = (f32x4){0.f,0.f,0.f,0.f};

#pragma unroll
        for (int ir = 0; ir < SROWS; ++ir) {
            const int sb = ir*ROWSH + abase;
            const int klo = (ir > 7) ? (ir-7) : 0;
            const int khi = (ir < 6) ? ir : 6;
            const bf16x4 h0 = *(const bf16x4*)(sh_hi + sb);
            const bf16x4 h1 = *(const bf16x4*)(sh_hi + sb + 4);
            const bf16x8 ah = __builtin_shufflevector(h0,h1,0,1,2,3,4,5,6,7);
#pragma unroll
            for (int kh = klo; kh <= khi; ++kh)
                acc[ir-kh] = MFMA16(ah, bw[kh], acc[ir-kh]);
            const bf16x4 l0 = *(const bf16x4*)(sh_lo + sb);
            const bf16x4 l1 = *(const bf16x4*)(sh_lo + sb + 4);
            const bf16x8 al = __builtin_shufflevector(l0,l1,0,1,2,3,4,5,6,7);
#pragma unroll
            for (int kh = klo; kh <= khi; ++kh)
                acc[ir-kh] = MFMA16(al, bw[kh], acc[ir-kh]);
        }

        float res[8][4];
#pragma unroll
        for (int cr = 0; cr < 8; ++cr)
#pragma unroll
            for (int r = 0; r < 4; ++r) {
                const float s = acc[cr][r];
                res[cr][r] = s + __shfl_xor(s, 8);
            }

        if (n16 < 8) {
#pragma unroll
            for (int pr = 0; pr < PROWS; ++pr) {
                const int ph = ph0 + pr;
                if (ph >= P1H) break;
#pragma unroll
                for (int q = 0; q < 2; ++q) {
                    const int pc = t*8 + 2*g + q;
                    if (pc < P1W) {
                        float m = fmaxf(fmaxf(res[2*pr][2*q], res[2*pr][2*q+1]),
                                        fmaxf(res[2*pr+1][2*q], res[2*pr+1][2*q+1]));
                        m = fmaxf(m + bias, 0.f);
                        const size_t oi = ((size_t)((b*P1H + ph)*P1W) + pc)*8 + n16;
                        const unsigned short hh = f2bf(m);
                        p1h[oi] = hh;
                        p1l[oi] = f2bf(m - bf2f(hh));
                    }
                }
            }
        }
    }
}

// ---------------------------------------------------------------------------
// conv2 5x5x8->10 + bias + relu + maxpool2, MFMA, 3-pass split. (unchanged)
__global__ __launch_bounds__(256) void conv2_kernel(
    const unsigned short* __restrict__ p1h, const unsigned short* __restrict__ p1l,
    const float* __restrict__ w2, const float* __restrict__ b2,
    float* __restrict__ p2)
{
    __shared__ char smem[10752 + 10752 + 7168 + 7168 + 128];
    short* sh_hi = (short*)smem;
    short* sh_lo = (short*)(smem + 10752);
    short* sh_bh = (short*)(smem + 21504);
    short* sh_bl = (short*)(smem + 28672);

    const int tid = threadIdx.x;
    const int ph  = blockIdx.x;
    const int b   = blockIdx.y;

    for (int i = tid; i < 7168; i += 256) ((short*)(smem + 21504))[i] = 0;
    __syncthreads();

    for (int i = tid; i < 2000; i += 256) {
        const float v = w2[i];
        const int kh = i / 400;
        int rem = i - kh*400;
        const int kw = rem / 80;
        rem -= kw*80;
        const int ci = rem / 10;
        const int co = rem - ci*10;
        const int k  = kh*40 + kw*8 + ci;
        const unsigned short h = f2bf(v);
        sh_bh[co*224 + k] = (short)h;
        sh_bl[co*224 + k] = (short)f2bf(v - bf2f(h));
    }

    const size_t gbase = ((size_t)b*P1H + 2*ph) * (P1W*8);
    const ulong2* gh = (const ulong2*)(p1h + gbase);
    const ulong2* gl = (const ulong2*)(p1l + gbase);
    ulong2* dh = (ulong2*)sh_hi;
    ulong2* dl = (ulong2*)sh_lo;
    for (int c = tid; c < 654; c += 256) {
        dh[c] = gh[c];
        dl[c] = gl[c];
    }
    for (int i = tid; i < 144; i += 256) {
        sh_hi[5232 + i] = 0;
        sh_lo[5232 + i] = 0;
    }
    __syncthreads();

    const int lane = tid & 63;
    const int wave = tid >> 6;
    const int n16  = lane & 15;
    const int g    = lane >> 4;

    bf16x8 bh[7], bl[7];
#pragma unroll
    for (int j = 0; j < 7; ++j) {
        bh[j] = *(const bf16x8*)(sh_bh + n16*224 + j*32 + g*8);
        bl[j] = *(const bf16x8*)(sh_bl + n16*224 + j*32 + g*8);
    }
    const float bias = (n16 < 10) ? b2[n16] : 0.f;

    int koff[7];
#pragma unroll
    for (int j = 0; j < 7; ++j) {
        const int chunk = 4*j + g;
        const int kh = chunk / 5;
        const int kw = chunk - kh*5;
        koff[j] = kh*872 + kw*8;
    }

    for (int t = wave; t < 7; t += 4) {
        const int c0 = t*16;
        const int pbase = (c0 + n16)*8;
        float res[2][4];
#pragma unroll
        for (int ro = 0; ro < 2; ++ro) {
            f32x4 accA = {0.f,0.f,0.f,0.f};
            f32x4 accB = {0.f,0.f,0.f,0.f};
            const int rb = ro*872 + pbase;
#pragma unroll
            for (int j = 0; j < 7; ++j) {
                const int si = rb + koff[j];
                const bf16x8 ah = *(const bf16x8*)(sh_hi + si);
                const bf16x8 al = *(const bf16x8*)(sh_lo + si);
                if (j & 1) {
                    accB = MFMA16(ah, bh[j], accB);
                    accB = MFMA16(al, bh[j], accB);
                    accB = MFMA16(ah, bl[j], accB);
                } else {
                    accA = MFMA16(ah, bh[j], accA);
                    accA = MFMA16(al, bh[j], accA);
                    accA = MFMA16(ah, bl[j], accA);
                }
            }
#pragma unroll
            for (int r = 0; r < 4; ++r) res[ro][r] = accA[r] + accB[r];
        }
        if (n16 < 10) {
#pragma unroll
            for (int q = 0; q < 2; ++q) {
                const int pc = (c0 >> 1) + 2*g + q;
                if (pc < P2W) {
                    float m = fmaxf(fmaxf(res[0][2*q], res[0][2*q+1]),
                                    fmaxf(res[1][2*q], res[1][2*q+1]));
                    p2[((size_t)((b*P2H + ph)*P2W) + pc)*10 + n16] = fmaxf(m + bias, 0.f);
                }
            }
        }
    }
}

// ---------------------------------------------------------------------------
__global__ __launch_bounds__(256) void fcA_kernel(
    const float* __restrict__ p2, const float* __restrict__ fw,
    float* __restrict__ partial)
{
    const int s = blockIdx.x;
    const int b = blockIdx.y;
    const int base = s * 3380;
    const float* f = p2 + (size_t)b*27040;
    float acc[6] = {0.f,0.f,0.f,0.f,0.f,0.f};
    for (int i = threadIdx.x; i < 3380; i += 256) {
        const float v = f[base + i];
        const float* wp = fw + (size_t)(base + i)*6;
#pragma unroll
        for (int k = 0; k < 6; ++k) acc[k] = fmaf(v, wp[k], acc[k]);
    }
    __shared__ float red[4][6];
#pragma unroll
    for (int k = 0; k < 6; ++k) {
        float v = acc[k];
        for (int off = 32; off > 0; off >>= 1) v += __shfl_down(v, off);
        if ((threadIdx.x & 63) == 0) red[threadIdx.x >> 6][k] = v;
    }
    __syncthreads();
    if (threadIdx.x < 6) {
        const int k = threadIdx.x;
        partial[(b*8 + s)*6 + k] = red[0][k] + red[1][k] + red[2][k] + red[3][k];
    }
}

__global__ __launch_bounds__(384) void fcB_kernel(
    const float* __restrict__ partial, const float* __restrict__ fb,
    float* __restrict__ theta)
{
    const int t = threadIdx.x;
    const int b = t / 6, k = t - b*6;
    float s = fb[k];
#pragma unroll
    for (int j = 0; j < 8; ++j) s += partial[(b*8 + j)*6 + k];
    theta[b*6 + k] = s;
}

// ---------------------------------------------------------------------------
__global__ __launch_bounds__(256) void resample_kernel(
    const float* __restrict__ x, const float* __restrict__ theta,
    float* __restrict__ out)
{
    const int idx = blockIdx.x * 256 + threadIdx.x;
    const int total = BATCH * HI * WI;
    if (idx >= total) return;
    const int b   = idx / (HI*WI);
    const int pix = idx - b * (HI*WI);
    const int yo  = pix / WI;
    const int xo  = pix - yo * WI;

    const float* t = theta + b*6;
    const float a0 = t[0], a1 = t[1], a2 = t[2], a3 = t[3], a4 = t[4], a5 = t[5];

    const float fx = (float)xo, fy = (float)yo;
    const float xq = a0*fx + a1*fy + a2;
    const float yq = a3*fx + a4*fy + a5;
    const float x0f = floorf(xq), y0f = floorf(yq);
    const float dx = xq - x0f, dy = yq - y0f;
    const int x0 = (int)x0f, y0 = (int)y0f;

    const float* img = x + (size_t)b * (HI*WI*3);

    const int x1 = x0 + 1, y1 = y0 + 1;
    const bool vx0 = (x0 >= 0) && (x0 <= WI-1);
    const bool vx1 = (x1 >= 0) && (x1 <= WI-1);
    const bool vy0 = (y0 >= 0) && (y0 <= HI-1);
    const bool vy1 = (y1 >= 0) && (y1 <= HI-1);
    const int xc0 = min(max(x0, 0), WI-1);
    const int xc1 = min(max(x1, 0), WI-1);
    const int yc0 = min(max(y0, 0), HI-1);
    const int yc1 = min(max(y1, 0), HI-1);
    const float* p00 = img + (size_t)(yc0*WI + xc0)*3;
    const float* p01 = img + (size_t)(yc0*WI + xc1)*3;
    const float* p10 = img + (size_t)(yc1*WI + xc0)*3;
    const float* p11 = img + (size_t)(yc1*WI + xc1)*3;
    const float m00 = (vy0 && vx0) ? 1.f : 0.f;
    const float m01 = (vy0 && vx1) ? 1.f : 0.f;
    const float m10 = (vy1 && vx0) ? 1.f : 0.f;
    const float m11 = (vy1 && vx1) ? 1.f : 0.f;

    float* op = out + (size_t)idx * 3;
#pragma unroll
    for (int c = 0; c < 3; ++c) {
        const float v00 = m00 * p00[c];
        const float v01 = m01 * p01[c];
        const float v10 = m10 * p10[c];
        const float v11 = m11 * p11[c];
        const float top = v00 * (1.f - dx) + v01 * dx;
        const float bot = v10 * (1.f - dx) + v11 * dx;
        op[c] = top * (1.f - dy) + bot * dy;
    }
}

// ---------------------------------------------------------------------------
extern "C" void kernel_launch(void* const* d_in, const int* in_sizes, int n_in,
                              void* d_out, int out_size, void* d_ws, size_t ws_size,
                              hipStream_t stream) {
    const float* x   = (const float*)d_in[0];
    const float* w1  = (const float*)d_in[1];
    const float* b1  = (const float*)d_in[2];
    const float* w2  = (const float*)d_in[3];
    const float* b2  = (const float*)d_in[4];
    const float* fw  = (const float*)d_in[5];
    const float* fb  = (const float*)d_in[6];
    float* out = (float*)d_out;

    char* ws = (char*)d_ws;
    unsigned short* p1h = (unsigned short*)ws;
    unsigned short* p1l = (unsigned short*)(ws + 12166144);
    float* p2      = (float*)(ws + 24332288);
    float* partial = (float*)(ws + 31254528);
    float* th      = (float*)(ws + 31266816);

    conv1_kernel<<<dim3(NROWG, BATCH), 256, 0, stream>>>(x, w1, b1, p1h, p1l);
    conv2_kernel<<<dim3(P2H, BATCH), 256, 0, stream>>>(p1h, p1l, w2, b2, p2);
    fcA_kernel<<<dim3(8, BATCH), 256, 0, stream>>>(p2, fw, partial);
    fcB_kernel<<<dim3(1), 384, 0, stream>>>(partial, fb, th);

    const int total_pix = BATCH * HI * WI;
    resample_kernel<<<dim3((total_pix + 255)/256), 256, 0, stream>>>(x, th, out);
}

// Round 6
// 76.756 us; speedup vs baseline: 2.6929x; 1.4701x over previous
//
#include <hip/hip_runtime.h>
#include <math.h>

#define BATCH 64
#define HI 224
#define WI 224
#define P1H 109
#define P1W 109
#define P2H 52
#define P2W 52

typedef _Float16 f16;
typedef _Float16 f16x4 __attribute__((ext_vector_type(4)));
typedef _Float16 f16x8 __attribute__((ext_vector_type(8)));
typedef float    f32x4 __attribute__((ext_vector_type(4)));

#define MFMA16F(a,b,c) __builtin_amdgcn_mfma_f32_16x16x32_f16((a),(b),(c),0,0,0)

// ---------------------------------------------------------------------------
// conv1 7x7x3->8 + bias + relu + maxpool2.  MFMA 16x16x32 f16 (fp32 acc).
// fp16 (10-bit mantissa) keeps conv-path rel error ~0.2% -> theta error well
// under the 0.085 output threshold (bf16's 8 bits failed at 0.117 in R5).
// Block = 4 pooled rows (8 conv rows, 14 input rows); acc for all 8 conv rows
// so each A-fragment feeds up to 7 MFMAs (kh reuse).
// K per input row = kw*4+ci (32 exactly; kw=7 / ci=3 slots zero-weighted).
#define PROWS 4
#define NROWG 28                      // ceil(109/4)
#define SROWS 14
#define ROWSH 896                     // f16 per staged row (224 cols * 4)
#define STOT  (SROWS*ROWSH)           // 12544
#define SPAD  12576                   // +32 zero elems for tile-13 overrun
__global__ __launch_bounds__(256) void conv1_kernel(
    const float* __restrict__ x, const float* __restrict__ w1,
    const float* __restrict__ b1,
    f16* __restrict__ p1)
{
    __shared__ f16 smem[SPAD + 7*16*32];     // (12576 + 3584)*2B = 32320 B
    f16* sh_a = smem;
    f16* sh_b = smem + SPAD;                 // [7 kh][16 n][32 k], n>=8 zero

    const int tid  = threadIdx.x;
    const int lane = tid & 63;
    const int wave = tid >> 6;
    const int bph  = blockIdx.x;
    const int b    = blockIdx.y;
    const int ph0  = PROWS*bph;
    const int ir0  = 2*ph0;

    for (int i = tid; i < 7*16*32; i += 256) sh_b[i] = (f16)0.f;
    __syncthreads();

    // weights: w1 HWIO (7,7,3,8) -> sh_b[(kh*16+co)*32 + kw*4 + ci]
    for (int i = tid; i < 1176; i += 256) {
        const float v = w1[i];
        const int co = i & 7;
        const int t3 = i >> 3;
        const int ci = t3 % 3;
        const int kk = t3 / 3;
        const int kh = kk / 7;
        const int kw = kk - kh*7;
        sh_b[(kh*16 + co)*32 + kw*4 + ci] = (f16)v;
    }

    // staging: lane writes 8 consecutive dest f16 (2 cols * 4 slots), linear.
    for (int u = wave; u < 25; u += 4) {
        const int q = u*512 + lane*8;
        if (q >= SPAD) continue;
        const int row  = q / ROWSH;
        const int rem  = q - row*ROWSH;
        const int col0 = rem >> 2;
        const int ira  = ir0 + row;
        float f0=0.f,f1=0.f,f2=0.f,f3=0.f,f4=0.f,f5=0.f;
        if (q < STOT && ira < HI) {
            const float* src = x + ((size_t)(b*HI + ira)*WI + col0)*3;
            const float2 a = *(const float2*)(src);
            const float2 c = *(const float2*)(src+2);
            const float2 e = *(const float2*)(src+4);
            f0=a.x; f1=a.y; f2=c.x; f3=c.y; f4=e.x; f5=e.y;
        }
        f16x8 hv;
        hv[0]=(f16)f0; hv[1]=(f16)f1; hv[2]=(f16)f2; hv[3]=(f16)0.f;
        hv[4]=(f16)f3; hv[5]=(f16)f4; hv[6]=(f16)f5; hv[7]=(f16)0.f;
        *(f16x8*)(sh_a + q) = hv;
    }
    __syncthreads();

    const int n16 = lane & 15;
    const int g   = lane >> 4;

    f16x8 bw[7];
#pragma unroll
    for (int kh = 0; kh < 7; ++kh)
        bw[kh] = *(const f16x8*)(sh_b + (kh*16 + n16)*32 + g*8);
    const float bias = b1[n16 & 7];

    for (int t = wave; t < 14; t += 4) {
        const int abase = (t*16 + n16)*4 + g*8;
        f32x4 acc[8];
#pragma unroll
        for (int cr = 0; cr < 8; ++cr) acc[cr] = (f32x4){0.f,0.f,0.f,0.f};

#pragma unroll
        for (int ir = 0; ir < SROWS; ++ir) {
            const int sb = ir*ROWSH + abase;
            const int klo = (ir > 7) ? (ir-7) : 0;
            const int khi = (ir < 6) ? ir : 6;
            const f16x4 h0 = *(const f16x4*)(sh_a + sb);
            const f16x4 h1 = *(const f16x4*)(sh_a + sb + 4);
            const f16x8 ah = __builtin_shufflevector(h0,h1,0,1,2,3,4,5,6,7);
#pragma unroll
            for (int kh = klo; kh <= khi; ++kh)
                acc[ir-kh] = MFMA16F(ah, bw[kh], acc[ir-kh]);
        }

        if (n16 < 8) {
#pragma unroll
            for (int pr = 0; pr < PROWS; ++pr) {
                const int ph = ph0 + pr;
                if (ph >= P1H) break;
#pragma unroll
                for (int q = 0; q < 2; ++q) {
                    const int pc = t*8 + 2*g + q;
                    if (pc < P1W) {
                        float m = fmaxf(fmaxf(acc[2*pr][2*q], acc[2*pr][2*q+1]),
                                        fmaxf(acc[2*pr+1][2*q], acc[2*pr+1][2*q+1]));
                        m = fmaxf(m + bias, 0.f);
                        const size_t oi = ((size_t)((b*P1H + ph)*P1W) + pc)*8 + n16;
                        p1[oi] = (f16)m;
                    }
                }
            }
        }
    }
}

// ---------------------------------------------------------------------------
// conv2 5x5x8->10 + bias + relu + maxpool2, MFMA f16 single-pass.
// K = kh*40 + kw*8 + ci (=200, padded to 224 with zero weights).
#define C2A 6144                       // sh_a f16 count (covers kh=5 phantom)
__global__ __launch_bounds__(256) void conv2_kernel(
    const f16* __restrict__ p1,
    const float* __restrict__ w2, const float* __restrict__ b2,
    float* __restrict__ p2)
{
    __shared__ f16 smem[C2A + 16*224];       // (6144 + 3584)*2B = 19456 B
    f16* sh_a = smem;
    f16* sh_b = smem + C2A;

    const int tid = threadIdx.x;
    const int ph  = blockIdx.x;
    const int b   = blockIdx.y;

    for (int i = tid; i < 16*224; i += 256) sh_b[i] = (f16)0.f;
    for (int i = tid; i < C2A - 5232; i += 256) sh_a[5232 + i] = (f16)0.f;
    __syncthreads();

    for (int i = tid; i < 2000; i += 256) {    // w2 HWIO (5,5,8,10)
        const float v = w2[i];
        const int kh = i / 400;
        int rem = i - kh*400;
        const int kw = rem / 80;
        rem -= kw*80;
        const int ci = rem / 10;
        const int co = rem - ci*10;
        sh_b[co*224 + kh*40 + kw*8 + ci] = (f16)v;
    }

    // stage p1 rows 2ph..2ph+5 (contiguous 5232 f16)
    const size_t gbase = ((size_t)b*P1H + 2*ph) * (P1W*8);
    const ulong2* gsrc = (const ulong2*)(p1 + gbase);
    ulong2* gdst = (ulong2*)sh_a;
    for (int c = tid; c < 654; c += 256) gdst[c] = gsrc[c];
    __syncthreads();

    const int lane = tid & 63;
    const int wave = tid >> 6;
    const int n16  = lane & 15;
    const int g    = lane >> 4;

    f16x8 bh[7];
#pragma unroll
    for (int j = 0; j < 7; ++j)
        bh[j] = *(const f16x8*)(sh_b + n16*224 + j*32 + g*8);
    const float bias = (n16 < 10) ? b2[n16] : 0.f;

    int koff[7];
#pragma unroll
    for (int j = 0; j < 7; ++j) {              // chunk = 4j+g -> (kh,kw)
        const int chunk = 4*j + g;
        const int kh = chunk / 5;
        const int kw = chunk - kh*5;
        koff[j] = kh*872 + kw*8;               // kh==5 phantom: zero B, zero A-pad
    }

    for (int t = wave; t < 7; t += 4) {
        const int c0 = t*16;
        const int pbase = (c0 + n16)*8;
        float res[2][4];
#pragma unroll
        for (int ro = 0; ro < 2; ++ro) {
            f32x4 accA = {0.f,0.f,0.f,0.f};
            f32x4 accB = {0.f,0.f,0.f,0.f};
            const int rb = ro*872 + pbase;
#pragma unroll
            for (int j = 0; j < 7; ++j) {
                const int si = rb + koff[j];
                const f16x8 ah = *(const f16x8*)(sh_a + si);
                if (j & 1) accB = MFMA16F(ah, bh[j], accB);
                else       accA = MFMA16F(ah, bh[j], accA);
            }
#pragma unroll
            for (int r = 0; r < 4; ++r) res[ro][r] = accA[r] + accB[r];
        }
        if (n16 < 10) {
#pragma unroll
            for (int q = 0; q < 2; ++q) {
                const int pc = (c0 >> 1) + 2*g + q;
                if (pc < P2W) {
                    float m = fmaxf(fmaxf(res[0][2*q], res[0][2*q+1]),
                                    fmaxf(res[1][2*q], res[1][2*q+1]));
                    p2[((size_t)((b*P2H + ph)*P2W) + pc)*10 + n16] = fmaxf(m + bias, 0.f);
                }
            }
        }
    }
}

// ---------------------------------------------------------------------------
__global__ __launch_bounds__(256) void fcA_kernel(
    const float* __restrict__ p2, const float* __restrict__ fw,
    float* __restrict__ partial)
{
    const int s = blockIdx.x;
    const int b = blockIdx.y;
    const int base = s * 3380;
    const float* f = p2 + (size_t)b*27040;
    float acc[6] = {0.f,0.f,0.f,0.f,0.f,0.f};
    for (int i = threadIdx.x; i < 3380; i += 256) {
        const float v = f[base + i];
        const float* wp = fw + (size_t)(base + i)*6;
#pragma unroll
        for (int k = 0; k < 6; ++k) acc[k] = fmaf(v, wp[k], acc[k]);
    }
    __shared__ float red[4][6];
#pragma unroll
    for (int k = 0; k < 6; ++k) {
        float v = acc[k];
        for (int off = 32; off > 0; off >>= 1) v += __shfl_down(v, off);
        if ((threadIdx.x & 63) == 0) red[threadIdx.x >> 6][k] = v;
    }
    __syncthreads();
    if (threadIdx.x < 6) {
        const int k = threadIdx.x;
        partial[(b*8 + s)*6 + k] = red[0][k] + red[1][k] + red[2][k] + red[3][k];
    }
}

__global__ __launch_bounds__(384) void fcB_kernel(
    const float* __restrict__ partial, const float* __restrict__ fb,
    float* __restrict__ theta)
{
    const int t = threadIdx.x;
    const int b = t / 6, k = t - b*6;
    float s = fb[k];
#pragma unroll
    for (int j = 0; j < 8; ++j) s += partial[(b*8 + j)*6 + k];
    theta[b*6 + k] = s;
}

// ---------------------------------------------------------------------------
__global__ __launch_bounds__(256) void resample_kernel(
    const float* __restrict__ x, const float* __restrict__ theta,
    float* __restrict__ out)
{
    const int idx = blockIdx.x * 256 + threadIdx.x;
    const int total = BATCH * HI * WI;
    if (idx >= total) return;
    const int b   = idx / (HI*WI);
    const int pix = idx - b * (HI*WI);
    const int yo  = pix / WI;
    const int xo  = pix - yo * WI;

    const float* t = theta + b*6;
    const float a0 = t[0], a1 = t[1], a2 = t[2], a3 = t[3], a4 = t[4], a5 = t[5];

    const float fx = (float)xo, fy = (float)yo;
    const float xq = a0*fx + a1*fy + a2;
    const float yq = a3*fx + a4*fy + a5;
    const float x0f = floorf(xq), y0f = floorf(yq);
    const float dx = xq - x0f, dy = yq - y0f;
    const int x0 = (int)x0f, y0 = (int)y0f;

    const float* img = x + (size_t)b * (HI*WI*3);

    const int x1 = x0 + 1, y1 = y0 + 1;
    const bool vx0 = (x0 >= 0) && (x0 <= WI-1);
    const bool vx1 = (x1 >= 0) && (x1 <= WI-1);
    const bool vy0 = (y0 >= 0) && (y0 <= HI-1);
    const bool vy1 = (y1 >= 0) && (y1 <= HI-1);
    const int xc0 = min(max(x0, 0), WI-1);
    const int xc1 = min(max(x1, 0), WI-1);
    const int yc0 = min(max(y0, 0), HI-1);
    const int yc1 = min(max(y1, 0), HI-1);
    const float* p00 = img + (size_t)(yc0*WI + xc0)*3;
    const float* p01 = img + (size_t)(yc0*WI + xc1)*3;
    const float* p10 = img + (size_t)(yc1*WI + xc0)*3;
    const float* p11 = img + (size_t)(yc1*WI + xc1)*3;
    const float m00 = (vy0 && vx0) ? 1.f : 0.f;
    const float m01 = (vy0 && vx1) ? 1.f : 0.f;
    const float m10 = (vy1 && vx0) ? 1.f : 0.f;
    const float m11 = (vy1 && vx1) ? 1.f : 0.f;

    float* op = out + (size_t)idx * 3;
#pragma unroll
    for (int c = 0; c < 3; ++c) {
        const float v00 = m00 * p00[c];
        const float v01 = m01 * p01[c];
        const float v10 = m10 * p10[c];
        const float v11 = m11 * p11[c];
        const float top = v00 * (1.f - dx) + v01 * dx;
        const float bot = v10 * (1.f - dx) + v11 * dx;
        op[c] = top * (1.f - dy) + bot * dy;
    }
}

// ---------------------------------------------------------------------------
extern "C" void kernel_launch(void* const* d_in, const int* in_sizes, int n_in,
                              void* d_out, int out_size, void* d_ws, size_t ws_size,
                              hipStream_t stream) {
    const float* x   = (const float*)d_in[0];
    const float* w1  = (const float*)d_in[1];
    const float* b1  = (const float*)d_in[2];
    const float* w2  = (const float*)d_in[3];
    const float* b2  = (const float*)d_in[4];
    const float* fw  = (const float*)d_in[5];
    const float* fb  = (const float*)d_in[6];
    float* out = (float*)d_out;

    char* ws = (char*)d_ws;
    f16*  p1      = (f16*)ws;                                // 12,166,144 B
    float* p2     = (float*)(ws + 12166144);                 //  6,922,240 B
    float* partial= (float*)(ws + 19088384);                 //     12,288 B
    float* th     = (float*)(ws + 19100672);                 //      1,536 B

    conv1_kernel<<<dim3(NROWG, BATCH), 256, 0, stream>>>(x, w1, b1, p1);
    conv2_kernel<<<dim3(P2H, BATCH), 256, 0, stream>>>(p1, w2, b2, p2);
    fcA_kernel<<<dim3(8, BATCH), 256, 0, stream>>>(p2, fw, partial);
    fcB_kernel<<<dim3(1), 384, 0, stream>>>(partial, fb, th);

    const int total_pix = BATCH * HI * WI;
    resample_kernel<<<dim3((total_pix + 255)/256), 256, 0, stream>>>(x, th, out);
}